// Round 7
// baseline (151.098 us; speedup 1.0000x reference)
//
#include <hip/hip_runtime.h>
#include <hip/hip_bf16.h>

typedef short s16x8 __attribute__((ext_vector_type(8)));
typedef short s16x4 __attribute__((ext_vector_type(4)));
typedef float f32x4 __attribute__((ext_vector_type(4)));
typedef unsigned short u16;

namespace {

constexpr int NHEAD = 4;
constexpr int CDIM  = 128;
constexpr int NTOK  = 49;
constexpr int IMG   = 56;
constexpr int NWIN  = 4096;   // 64 batches x 8x8 windows; 1 wave each
constexpr float QSCALE = 0.17677669529663687f;  // 32^-0.5

__device__ inline u16 f2bf(float x) {
  union { __hip_bfloat16 b; u16 u; } cv;
  cv.b = __float2bfloat16(x);          // RNE; compiler can fuse v_cvt_pk_bf16_f32
  return cv.u;
}
__device__ inline float bf2f(u16 h) { return __uint_as_float(((unsigned)h) << 16); }
__device__ inline int div7(int t) { return (t * 9363) >> 16; }  // valid t<64

__device__ inline f32x4 mfma32(s16x8 a, s16x8 b, f32x4 c) {
  return __builtin_amdgcn_mfma_f32_16x16x32_bf16(a, b, c, 0, 0, 0);
}
__device__ inline f32x4 mfma16(s16x4 a, s16x4 b, f32x4 c) {
#if __has_builtin(__builtin_amdgcn_mfma_f32_16x16x16bf16_1k)
  return __builtin_amdgcn_mfma_f32_16x16x16bf16_1k(a, b, c, 0, 0, 0);
#else
  f32x4 d;
  asm volatile("v_mfma_f32_16x16x16_bf16 %0, %1, %2, %3"
               : "=v"(d) : "v"(a), "v"(b), "v"(c));
  return d;
#endif
}
__device__ inline s16x4 pack4(f32x4 v) {
  s16x4 r;
  r[0] = (short)f2bf(v[0]); r[1] = (short)f2bf(v[1]);
  r[2] = (short)f2bf(v[2]); r[3] = (short)f2bf(v[3]);
  return r;
}

// ---- prep: bf16 weights + combined bias/mask/pad table (L2-resident) ----
__global__ void prep(const float* __restrict__ qkvw, const float* __restrict__ projw,
                     const float* __restrict__ rpb,
                     u16* __restrict__ wq, u16* __restrict__ wp, u16* __restrict__ btab) {
  int i = blockIdx.x * 256 + threadIdx.x;
  if (i < 384 * 128) wq[i] = f2bf(qkvw[i]);
  if (i < 128 * 128) wp[i] = f2bf(projw[i]);
  if (i < 65536) {
    int m = i & 63, n = (i >> 6) & 63, h = (i >> 12) & 3, cls = (i >> 14) & 3;
    float v;
    if (m >= NTOK) v = -1e9f;           // key-pad: excluded from softmax
    else if (n >= NTOK) v = 0.f;        // query-pad: don't-care (never stored)
    else {
      int tin = div7(n), tjn = n - tin * 7;
      int tim = div7(m), tjm = m - tim * 7;
      int ridx = 13 * (tin - tim + 6) + (tjn - tjm + 6);
      v = rpb[ridx * NHEAD + h];
      int wy = (cls & 2) ? 7 : 0, wx = (cls & 1) ? 7 : 0;
      int mhn = wy * 7 + tin, mwn = wx * 7 + tjn;
      int mhm = wy * 7 + tim, mwm = wx * 7 + tjm;
      int cn = ((mhn < 49) ? 0 : ((mhn < 53) ? 1 : 2)) * 3 + ((mwn < 49) ? 0 : ((mwn < 53) ? 1 : 2));
      int cm = ((mhm < 49) ? 0 : ((mhm < 53) ? 1 : 2)) * 3 + ((mwm < 49) ? 0 : ((mwm < 53) ? 1 : 2));
      if (cn != cm) v -= 100.f;
    }
    btab[i] = f2bf(v);
  }
}

__global__ __launch_bounds__(64, 2) void swin_wave(
    const float* __restrict__ xin,    // [64][3136][128] f32
    const float* __restrict__ qkvb,   // [384]
    const float* __restrict__ projb,  // [128]
    const u16*  __restrict__ wq,      // [384][128] bf16 (Q|K|V row-major)
    const u16*  __restrict__ wp,      // [128][128] bf16
    const u16*  __restrict__ btab,    // [4][4][64][64] bf16, [n][m]
    float* __restrict__ outp)         // [64][3136][128] f32
{
  const int wb = blockIdx.x;
  const int bb = wb >> 6, wy = (wb >> 3) & 7, wx = wb & 7;
  const int lane = threadIdx.x;
  const int g = lane >> 4, lj = lane & 15;
  const int cls = ((wy == 7) ? 2 : 0) | ((wx == 7) ? 1 : 0);

  auto gposf = [&](int tok) -> int {
    int t  = (tok < NTOK) ? tok : 0;
    int ti = div7(t), tj = t - ti * 7;
    int gh = wy * 7 + ti + 3; if (gh >= IMG) gh -= IMG;
    int gw = wx * 7 + tj + 3; if (gw >= IMG) gw -= IMG;
    return gh * IMG + gw;
  };

  // ---- X: whole window in regs, bf16. X[mt][ks] = rows 16mt+lj, c=32ks+8g..+7
  const float* xb = xin + (size_t)bb * (IMG * IMG * CDIM);
  s16x8 X[4][4];
  #pragma unroll
  for (int mt = 0; mt < 4; ++mt) {
    int tok = 16 * mt + lj;
    bool ok = tok < NTOK;
    const float* xr = xb + (size_t)gposf(tok) * CDIM;
    #pragma unroll
    for (int ks = 0; ks < 4; ++ks) {
      s16x8 r = {0, 0, 0, 0, 0, 0, 0, 0};
      if (ok) {
        float4 a = *reinterpret_cast<const float4*>(xr + 32 * ks + 8 * g);
        float4 b = *reinterpret_cast<const float4*>(xr + 32 * ks + 8 * g + 4);
        r[0] = (short)f2bf(a.x); r[1] = (short)f2bf(a.y);
        r[2] = (short)f2bf(a.z); r[3] = (short)f2bf(a.w);
        r[4] = (short)f2bf(b.x); r[5] = (short)f2bf(b.y);
        r[6] = (short)f2bf(b.z); r[7] = (short)f2bf(b.w);
      }
      X[mt][ks] = r;
    }
  }

  // oa[nt][kp]: A-frag(o) of the attention output, filled directly from C(out^T)
  // (identity: C(out^T) tile (dt,nt) == A-frag(o)[row-tile nt][k-tile 2h+dt])
  s16x4 oa[4][8];

  #pragma unroll
  for (int h = 0; h < NHEAD; ++h) {
    // ---- K^T = Wk . X^T  (C(K^T) == A-frag(K)) ----
    s16x4 Kbf[4][2];
    #pragma unroll
    for (int dt = 0; dt < 2; ++dt) {
      s16x8 wa[4];
      #pragma unroll
      for (int ks = 0; ks < 4; ++ks)
        wa[ks] = *reinterpret_cast<const s16x8*>(
            &wq[(size_t)(128 + 32 * h + 16 * dt + lj) * 128 + 32 * ks + 8 * g]);
      f32x4 bk4 = *reinterpret_cast<const f32x4*>(&qkvb[128 + 32 * h + 16 * dt + 4 * g]);
      #pragma unroll
      for (int mt = 0; mt < 4; ++mt) {
        f32x4 c = {0.f, 0.f, 0.f, 0.f};
        #pragma unroll
        for (int ks = 0; ks < 4; ++ks) c = mfma32(wa[ks], X[mt][ks], c);
        Kbf[mt][dt] = pack4(c + bk4);
      }
    }
    // ---- Q^T = Wq . X^T  (C(Q^T) == B-frag(Q^T)) ----
    s16x4 Qbf[2][4];
    #pragma unroll
    for (int dt = 0; dt < 2; ++dt) {
      s16x8 wa[4];
      #pragma unroll
      for (int ks = 0; ks < 4; ++ks)
        wa[ks] = *reinterpret_cast<const s16x8*>(
            &wq[(size_t)(32 * h + 16 * dt + lj) * 128 + 32 * ks + 8 * g]);
      f32x4 bq4 = *reinterpret_cast<const f32x4*>(&qkvb[32 * h + 16 * dt + 4 * g]);
      #pragma unroll
      for (int nt = 0; nt < 4; ++nt) {
        f32x4 c = {0.f, 0.f, 0.f, 0.f};
        #pragma unroll
        for (int ks = 0; ks < 4; ++ks) c = mfma32(wa[ks], X[nt][ks], c);
        f32x4 q;
        #pragma unroll
        for (int r2 = 0; r2 < 4; ++r2) q[r2] = (c[r2] + bq4[r2]) * QSCALE;
        Qbf[dt][nt] = pack4(q);
      }
    }
    // ---- V = X . Wv^T  (C(V) == A-frag(V^T)) ----
    s16x4 Vbf[4][2];
    #pragma unroll
    for (int dt = 0; dt < 2; ++dt) {
      s16x8 wbv[4];
      #pragma unroll
      for (int ks = 0; ks < 4; ++ks)
        wbv[ks] = *reinterpret_cast<const s16x8*>(
            &wq[(size_t)(256 + 32 * h + 16 * dt + lj) * 128 + 32 * ks + 8 * g]);
      float bv = qkvb[256 + 32 * h + 16 * dt + lj];
      #pragma unroll
      for (int mt = 0; mt < 4; ++mt) {
        f32x4 c = {0.f, 0.f, 0.f, 0.f};
        #pragma unroll
        for (int ks = 0; ks < 4; ++ks) c = mfma32(X[mt][ks], wbv[ks], c);
        f32x4 v;
        #pragma unroll
        for (int r2 = 0; r2 < 4; ++r2) v[r2] = c[r2] + bv;
        Vbf[mt][dt] = pack4(v);
      }
    }
    // ---- per n-tile: S^T = K.Q^T, softmax over m, out^T = V^T.P^T -> oa ----
    const u16* bt = btab + (((cls << 2) + h) << 12);
    #pragma unroll
    for (int nt = 0; nt < 4; ++nt) {
      f32x4 st[4];
      #pragma unroll
      for (int mt = 0; mt < 4; ++mt) {
        f32x4 c = mfma16(Kbf[mt][0], Qbf[0][nt], (f32x4){0.f, 0.f, 0.f, 0.f});
        c = mfma16(Kbf[mt][1], Qbf[1][nt], c);
        s16x4 bb4 = *reinterpret_cast<const s16x4*>(&bt[((16 * nt + lj) << 6) + 16 * mt + 4 * g]);
        #pragma unroll
        for (int r2 = 0; r2 < 4; ++r2) c[r2] += bf2f((u16)bb4[r2]);
        st[mt] = c;
      }
      float mx = -3e38f;
      #pragma unroll
      for (int mt = 0; mt < 4; ++mt)
        #pragma unroll
        for (int r2 = 0; r2 < 4; ++r2) mx = fmaxf(mx, st[mt][r2]);
      mx = fmaxf(mx, __shfl_xor(mx, 16, 64));
      mx = fmaxf(mx, __shfl_xor(mx, 32, 64));
      float sm = 0.f;
      #pragma unroll
      for (int mt = 0; mt < 4; ++mt)
        #pragma unroll
        for (int r2 = 0; r2 < 4; ++r2) {
          float e = __expf(st[mt][r2] - mx);
          st[mt][r2] = e;
          sm += e;
        }
      sm += __shfl_xor(sm, 16, 64);
      sm += __shfl_xor(sm, 32, 64);
      float inv = 1.f / sm;
      s16x4 Pt[4];
      #pragma unroll
      for (int mt = 0; mt < 4; ++mt) {
        f32x4 p;
        #pragma unroll
        for (int r2 = 0; r2 < 4; ++r2) p[r2] = st[mt][r2] * inv;
        Pt[mt] = pack4(p);
      }
      #pragma unroll
      for (int dt = 0; dt < 2; ++dt) {
        f32x4 oc = {0.f, 0.f, 0.f, 0.f};
        #pragma unroll
        for (int mt = 0; mt < 4; ++mt) oc = mfma16(Vbf[mt][dt], Pt[mt], oc);
        oa[nt][2 * h + dt] = pack4(oc);   // static index: h, nt, dt all unrolled
      }
    }
  }

  // ---- proj: y = o . Wp^T, straight from oa registers; scatter to global ----
  int gp[4][4];
  bool tv[4][4];
  #pragma unroll
  for (int nt = 0; nt < 4; ++nt)
    #pragma unroll
    for (int r2 = 0; r2 < 4; ++r2) {
      int tok = 16 * nt + 4 * g + r2;
      gp[nt][r2] = gposf(tok);
      tv[nt][r2] = tok < NTOK;
    }
  float* ob = outp + (size_t)bb * (IMG * IMG * CDIM);
  #pragma unroll 1
  for (int ct = 0; ct < 8; ++ct) {
    s16x4 wpb[8];
    #pragma unroll
    for (int kp = 0; kp < 8; ++kp)
      wpb[kp] = *reinterpret_cast<const s16x4*>(
          &wp[(size_t)(16 * ct + lj) * 128 + 16 * kp + 4 * g]);
    float bias = projb[16 * ct + lj];
    #pragma unroll
    for (int nt = 0; nt < 4; ++nt) {
      f32x4 y = {0.f, 0.f, 0.f, 0.f};
      #pragma unroll
      for (int kp = 0; kp < 8; ++kp) y = mfma16(oa[nt][kp], wpb[kp], y);
      #pragma unroll
      for (int r2 = 0; r2 < 4; ++r2)
        if (tv[nt][r2])
          ob[(size_t)gp[nt][r2] * CDIM + 16 * ct + lj] = y[r2] + bias;
    }
  }
}

}  // namespace

extern "C" void kernel_launch(void* const* d_in, const int* in_sizes, int n_in,
                              void* d_out, int out_size, void* d_ws, size_t ws_size,
                              hipStream_t stream) {
  const float* x     = (const float*)d_in[0];
  const float* rpb   = (const float*)d_in[1];
  const float* qkvw  = (const float*)d_in[2];
  const float* qkvb  = (const float*)d_in[3];
  const float* projw = (const float*)d_in[4];
  const float* projb = (const float*)d_in[5];
  u16* wq   = (u16*)d_ws;                 // 384*128
  u16* wp   = wq + 384 * 128;             // 128*128
  u16* btab = wp + 128 * 128;             // 4*4*64*64

  prep<<<256, 256, 0, stream>>>(qkvw, projw, rpb, wq, wp, btab);
  swin_wave<<<NWIN, 64, 0, stream>>>(x, qkvb, projb, wq, wp, btab, (float*)d_out);
}